// Round 1
// baseline (140.442 us; speedup 1.0000x reference)
//
#include <hip/hip_runtime.h>

#define H   384
#define W   1280
#define PH  192
#define PW  640
#define PP  (PH*PW)      // 122880 pixels per pooled plane

// ---------------------------------------------------------------------------
// Kernel A: 2x2 average pool + RGB->YCbCr for both images, both batches.
// Plane index p = img*2 + n  (img: 0=left, 1=right).
// Arithmetic uses explicit round-to-nearest intrinsics in numpy evaluation
// order so the census '>=' comparisons match the reference bit-for-bit.
// ---------------------------------------------------------------------------
__global__ __launch_bounds__(256) void pool_ycbcr_kernel(
    const float* __restrict__ left, const float* __restrict__ right,
    float* __restrict__ yp, float* __restrict__ cbp, float* __restrict__ crp)
{
    int tid = blockIdx.x * blockDim.x + threadIdx.x;
    if (tid >= 4 * PP) return;
    int p   = tid / PP;
    int rem = tid - p * PP;
    int y   = rem / PW;
    int x   = rem - y * PW;

    const float* src = (p < 2 ? left : right) + (size_t)(p & 1) * 3 * H * W;

    float pc[3];
#pragma unroll
    for (int c = 0; c < 3; ++c) {
        const float* ch = src + (size_t)c * H * W + (size_t)(2 * y) * W + 2 * x;
        float2 a = *(const float2*)ch;
        float2 b = *(const float2*)(ch + W);
        // numpy reduction order over the 2x2 block: ((x00+x01)+x10)+x11
        float s = __fadd_rn(__fadd_rn(__fadd_rn(a.x, a.y), b.x), b.y);
        pc[c] = __fmul_rn(s, 0.25f);
    }
    // y = 0.299*r + 0.587*g + 0.114*b   (left-to-right, no fma)
    float yv = __fadd_rn(__fadd_rn(__fmul_rn(0.299f, pc[0]),
                                   __fmul_rn(0.587f, pc[1])),
                         __fmul_rn(0.114f, pc[2]));
    float cb = __fadd_rn(__fmul_rn(__fsub_rn(pc[2], yv), 0.564f), 0.5f);
    float cr = __fadd_rn(__fmul_rn(__fsub_rn(pc[0], yv), 0.713f), 0.5f);

    yp[tid]  = yv;
    cbp[tid] = cb;
    crp[tid] = cr;
}

// ---------------------------------------------------------------------------
// Kernel B: 5x5 census transform (24 bits, MSB = offset (0,0)), zero border.
// ---------------------------------------------------------------------------
__global__ __launch_bounds__(256) void census_kernel(
    const float* __restrict__ yp, int* __restrict__ cen)
{
    int tid = blockIdx.x * blockDim.x + threadIdx.x;
    if (tid >= 4 * PP) return;
    int p   = tid / PP;
    int rem = tid - p * PP;
    int y   = rem / PW;
    int x   = rem - y * PW;

    int code = 0;
    if (y >= 2 && y < PH - 2 && x >= 2 && x < PW - 2) {
        const float* base = yp + (size_t)p * PP;
        float c = base[y * PW + x];
        int bit = 23;
#pragma unroll
        for (int v = 0; v < 5; ++v) {
#pragma unroll
            for (int u = 0; u < 5; ++u) {
                if (u == 2 && v == 2) continue;  // center excluded
                float nb = base[(y - 2 + v) * PW + (x - 2 + u)];
                code |= (nb >= c ? 1 : 0) << bit;
                --bit;
            }
        }
    }
    cen[tid] = code;
}

// ---------------------------------------------------------------------------
// Kernel C: cost volume + normalization, fused.
// out[n][g*128+d][y][x]:
//   g=0: (popcount(cenL[x+d]^cenR[x]) - 11.08282948)/0.1949711
//   g=1: (|cbL[x+d]-cbR[x]| - 0.02175535)/35.91432953
//   g=2: (|crL[x+d]-crR[x]| - 0.02679042)/26.79782867
// masked (x >= 640-d): value 0 before normalization.
// Grid: 2 (n) * 384 (ch) * 8 (y-tiles of 24 rows). float4 stores.
// ---------------------------------------------------------------------------
__global__ __launch_bounds__(256) void costvol_kernel(
    const float* __restrict__ cbp, const float* __restrict__ crp,
    const int* __restrict__ cen, float* __restrict__ out)
{
    const float m1 = 11.08282948f, i1 = 1.0f / 0.1949711f;
    const float m2 = 0.02175535f,  i2 = 1.0f / 35.91432953f;
    const float m3 = 0.02679042f,  i3 = 1.0f / 26.79782867f;

    int b  = blockIdx.x;
    int yt = b & 7;           // y tile (24 rows each)
    int t  = b >> 3;
    int n  = t / 384;
    int ch = t - n * 384;
    int g  = ch >> 7;         // 0=ham, 1=u, 2=v  (block-uniform)
    int d  = ch & 127;
    int nvalid = PW - d;
    int y0 = yt * 24;

    int pl = 0 * 2 + n;       // left plane
    int pr = 1 * 2 + n;       // right plane

    float* orow_base = out + ((size_t)(n * 384 + ch) * PH) * PW;

    if (g == 0) {
        const float c0 = (0.0f - m1) * i1;
        const int* L = cen + (size_t)pl * PP;
        const int* R = cen + (size_t)pr * PP;
        for (int i = threadIdx.x; i < 24 * 160; i += 256) {
            int y  = y0 + i / 160;
            int xq = i - (i / 160) * 160;
            int x0 = xq * 4;
            const int* Lr = L + y * PW;
            int4 rv = *(const int4*)(R + y * PW + x0);
            float ov[4];
            int rr[4] = {rv.x, rv.y, rv.z, rv.w};
#pragma unroll
            for (int j = 0; j < 4; ++j) {
                int xj = x0 + j;
                if (xj < nvalid) {
                    int lv = Lr[xj + d];
                    ov[j] = ((float)__popc(lv ^ rr[j]) - m1) * i1;
                } else {
                    ov[j] = c0;
                }
            }
            *(float4*)(orow_base + (size_t)y * PW + x0) =
                make_float4(ov[0], ov[1], ov[2], ov[3]);
        }
    } else {
        const float m = (g == 1) ? m2 : m3;
        const float iv = (g == 1) ? i2 : i3;
        const float c0 = (0.0f - m) * iv;
        const float* P = (g == 1) ? cbp : crp;
        const float* L = P + (size_t)pl * PP;
        const float* R = P + (size_t)pr * PP;
        for (int i = threadIdx.x; i < 24 * 160; i += 256) {
            int y  = y0 + i / 160;
            int xq = i - (i / 160) * 160;
            int x0 = xq * 4;
            const float* Lr = L + y * PW;
            float4 rv = *(const float4*)(R + y * PW + x0);
            float ov[4];
            float rr[4] = {rv.x, rv.y, rv.z, rv.w};
#pragma unroll
            for (int j = 0; j < 4; ++j) {
                int xj = x0 + j;
                if (xj < nvalid) {
                    float lv = Lr[xj + d];
                    ov[j] = (fabsf(lv - rr[j]) - m) * iv;
                } else {
                    ov[j] = c0;
                }
            }
            *(float4*)(orow_base + (size_t)y * PW + x0) =
                make_float4(ov[0], ov[1], ov[2], ov[3]);
        }
    }
}

// ---------------------------------------------------------------------------
extern "C" void kernel_launch(void* const* d_in, const int* in_sizes, int n_in,
                              void* d_out, int out_size, void* d_ws, size_t ws_size,
                              hipStream_t stream)
{
    const float* left  = (const float*)d_in[0];
    const float* right = (const float*)d_in[1];

    float* ws  = (float*)d_ws;
    float* yp  = ws;            // 4 planes (img,n) of PP floats
    float* cbp = ws + 4 * PP;
    float* crp = ws + 8 * PP;
    int*   cen = (int*)(ws + 12 * PP);   // 4 planes of PP int32

    int threads = 256;
    int blocksAB = (4 * PP + threads - 1) / threads;   // 1920

    pool_ycbcr_kernel<<<blocksAB, threads, 0, stream>>>(left, right, yp, cbp, crp);
    census_kernel<<<blocksAB, threads, 0, stream>>>(yp, cen);

    int blocksC = 2 * 384 * 8;   // 6144
    costvol_kernel<<<blocksC, threads, 0, stream>>>(cbp, crp, cen, (float*)d_out);
}

// Round 3
// 93.026 us; speedup vs baseline: 1.5097x; 1.5097x over previous
//
#include <hip/hip_runtime.h>

#define H   384
#define W   1280
#define PH  192
#define PW  640
#define PP  (PH*PW)      // 122880 pixels per pooled plane

typedef float f32x4 __attribute__((ext_vector_type(4)));
typedef int   i32x4 __attribute__((ext_vector_type(4)));

// ---------------------------------------------------------------------------
// Kernel A: 2x2 average pool + RGB->YCbCr for both images, both batches.
// Plane index p = img*2 + n  (img: 0=left, 1=right).
// Explicit round-to-nearest intrinsics in numpy evaluation order so the
// census '>=' comparisons match the reference bit-for-bit.
// ---------------------------------------------------------------------------
__global__ __launch_bounds__(256) void pool_ycbcr_kernel(
    const float* __restrict__ left, const float* __restrict__ right,
    float* __restrict__ yp, float* __restrict__ cbp, float* __restrict__ crp)
{
    int tid = blockIdx.x * blockDim.x + threadIdx.x;
    if (tid >= 4 * PP) return;
    int p   = tid / PP;
    int rem = tid - p * PP;
    int y   = rem / PW;
    int x   = rem - y * PW;

    const float* src = (p < 2 ? left : right) + (size_t)(p & 1) * 3 * H * W;

    float pc[3];
#pragma unroll
    for (int c = 0; c < 3; ++c) {
        const float* ch = src + (size_t)c * H * W + (size_t)(2 * y) * W + 2 * x;
        float2 a = *(const float2*)ch;
        float2 b = *(const float2*)(ch + W);
        float s = __fadd_rn(__fadd_rn(__fadd_rn(a.x, a.y), b.x), b.y);
        pc[c] = __fmul_rn(s, 0.25f);
    }
    float yv = __fadd_rn(__fadd_rn(__fmul_rn(0.299f, pc[0]),
                                   __fmul_rn(0.587f, pc[1])),
                         __fmul_rn(0.114f, pc[2]));
    float cb = __fadd_rn(__fmul_rn(__fsub_rn(pc[2], yv), 0.564f), 0.5f);
    float cr = __fadd_rn(__fmul_rn(__fsub_rn(pc[0], yv), 0.713f), 0.5f);

    yp[tid]  = yv;
    cbp[tid] = cb;
    crp[tid] = cr;
}

// ---------------------------------------------------------------------------
// Kernel B: 5x5 census transform (24 bits, MSB = offset (0,0)), zero border.
// ---------------------------------------------------------------------------
__global__ __launch_bounds__(256) void census_kernel(
    const float* __restrict__ yp, int* __restrict__ cen)
{
    int tid = blockIdx.x * blockDim.x + threadIdx.x;
    if (tid >= 4 * PP) return;
    int p   = tid / PP;
    int rem = tid - p * PP;
    int y   = rem / PW;
    int x   = rem - y * PW;

    int code = 0;
    if (y >= 2 && y < PH - 2 && x >= 2 && x < PW - 2) {
        const float* base = yp + (size_t)p * PP;
        float c = base[y * PW + x];
        int bit = 23;
#pragma unroll
        for (int v = 0; v < 5; ++v) {
#pragma unroll
            for (int u = 0; u < 5; ++u) {
                if (u == 2 && v == 2) continue;  // center excluded
                float nb = base[(y - 2 + v) * PW + (x - 2 + u)];
                code |= (nb >= c ? 1 : 0) << bit;
                --bit;
            }
        }
    }
    cen[tid] = code;
}

// ---------------------------------------------------------------------------
// Kernel C: cost volume + normalization, fused.
//   g=0: (popcount(cenL[x+d]^cenR[x]) - m1)/s1
//   g=1: (|cbL[x+d]-cbR[x]| - m2)/s2
//   g=2: (|crL[x+d]-crR[x]| - m3)/s3
// masked (x >= 640-d): 0 before normalization.
// Nontemporal float4 stores so the 377MB output stream does not evict the
// small L/R planes from L2 (they are re-read 128x per d-channel).
// Left-row loads: two aligned vec4 loads + block-uniform shift select.
// ---------------------------------------------------------------------------
__global__ __launch_bounds__(256) void costvol_kernel(
    const float* __restrict__ cbp, const float* __restrict__ crp,
    const int* __restrict__ cen, float* __restrict__ out)
{
    const float m1 = 11.08282948f, i1 = 1.0f / 0.1949711f;
    const float m2 = 0.02175535f,  i2 = 1.0f / 35.91432953f;
    const float m3 = 0.02679042f,  i3 = 1.0f / 26.79782867f;

    int b  = blockIdx.x;
    int yt = b & 7;           // y tile (24 rows each)
    int t  = b >> 3;
    int n  = t / 384;
    int ch = t - n * 384;
    int g  = ch >> 7;         // 0=ham, 1=u, 2=v  (block-uniform)
    int d  = ch & 127;
    int nvalid = PW - d;
    int y0 = yt * 24;
    int s  = d & 3;           // block-uniform shift
    int dal = d - s;          // aligned base offset
    const int tid = threadIdx.x;

    f32x4* ob = (f32x4*)(out + (((size_t)(n * 384 + ch)) * PH + y0) * PW);

    if (g == 0) {
        const float c0 = (0.0f - m1) * i1;
        const int* L = cen + (size_t)n * PP;        // left plane  (p = n)
        const int* R = cen + (size_t)(2 + n) * PP;  // right plane (p = 2+n)
#pragma unroll 5
        for (int k = 0; k < 15; ++k) {
            int i  = tid + 256 * k;
            int yy = i / 160;
            int x0 = (i - yy * 160) * 4;
            int row = (y0 + yy) * PW;
            i32x4 rv = *(const i32x4*)(R + row + x0);
            const int* Lp = L + row + x0 + dal;
            i32x4 A  = *(const i32x4*)(Lp);
            i32x4 Bv = *(const i32x4*)(Lp + 4);
            int e0, e1, e2, e3;
            if      (s == 0) { e0 = A.x;  e1 = A.y;  e2 = A.z;  e3 = A.w;  }
            else if (s == 1) { e0 = A.y;  e1 = A.z;  e2 = A.w;  e3 = Bv.x; }
            else if (s == 2) { e0 = A.z;  e1 = A.w;  e2 = Bv.x; e3 = Bv.y; }
            else             { e0 = A.w;  e1 = Bv.x; e2 = Bv.y; e3 = Bv.z; }
            f32x4 ov;
            ov.x = (x0 + 0 < nvalid) ? ((float)__popc(e0 ^ rv.x) - m1) * i1 : c0;
            ov.y = (x0 + 1 < nvalid) ? ((float)__popc(e1 ^ rv.y) - m1) * i1 : c0;
            ov.z = (x0 + 2 < nvalid) ? ((float)__popc(e2 ^ rv.z) - m1) * i1 : c0;
            ov.w = (x0 + 3 < nvalid) ? ((float)__popc(e3 ^ rv.w) - m1) * i1 : c0;
            __builtin_nontemporal_store(ov, ob + i);
        }
    } else {
        const float m  = (g == 1) ? m2 : m3;
        const float iv = (g == 1) ? i2 : i3;
        const float c0 = (0.0f - m) * iv;
        const float* P = (g == 1) ? cbp : crp;
        const float* L = P + (size_t)n * PP;
        const float* R = P + (size_t)(2 + n) * PP;
#pragma unroll 5
        for (int k = 0; k < 15; ++k) {
            int i  = tid + 256 * k;
            int yy = i / 160;
            int x0 = (i - yy * 160) * 4;
            int row = (y0 + yy) * PW;
            f32x4 rv = *(const f32x4*)(R + row + x0);
            const float* Lp = L + row + x0 + dal;
            f32x4 A  = *(const f32x4*)(Lp);
            f32x4 Bv = *(const f32x4*)(Lp + 4);
            float e0, e1, e2, e3;
            if      (s == 0) { e0 = A.x;  e1 = A.y;  e2 = A.z;  e3 = A.w;  }
            else if (s == 1) { e0 = A.y;  e1 = A.z;  e2 = A.w;  e3 = Bv.x; }
            else if (s == 2) { e0 = A.z;  e1 = A.w;  e2 = Bv.x; e3 = Bv.y; }
            else             { e0 = A.w;  e1 = Bv.x; e2 = Bv.y; e3 = Bv.z; }
            f32x4 ov;
            ov.x = (x0 + 0 < nvalid) ? (fabsf(e0 - rv.x) - m) * iv : c0;
            ov.y = (x0 + 1 < nvalid) ? (fabsf(e1 - rv.y) - m) * iv : c0;
            ov.z = (x0 + 2 < nvalid) ? (fabsf(e2 - rv.z) - m) * iv : c0;
            ov.w = (x0 + 3 < nvalid) ? (fabsf(e3 - rv.w) - m) * iv : c0;
            __builtin_nontemporal_store(ov, ob + i);
        }
    }
}

// ---------------------------------------------------------------------------
extern "C" void kernel_launch(void* const* d_in, const int* in_sizes, int n_in,
                              void* d_out, int out_size, void* d_ws, size_t ws_size,
                              hipStream_t stream)
{
    const float* left  = (const float*)d_in[0];
    const float* right = (const float*)d_in[1];

    float* ws  = (float*)d_ws;
    float* yp  = ws;                     // 4 planes of PP floats
    float* cbp = ws + 4 * PP;
    float* crp = ws + 8 * PP;
    int*   cen = (int*)(ws + 12 * PP);   // 4 planes of PP int32 (+pad row for
                                         // aligned-vector overread)

    int threads = 256;
    int blocksAB = (4 * PP + threads - 1) / threads;   // 1920

    pool_ycbcr_kernel<<<blocksAB, threads, 0, stream>>>(left, right, yp, cbp, crp);
    census_kernel<<<blocksAB, threads, 0, stream>>>(yp, cen);

    int blocksC = 2 * 384 * 8;   // 6144
    costvol_kernel<<<blocksC, threads, 0, stream>>>(cbp, crp, cen, (float*)d_out);
}

// Round 4
// 89.112 us; speedup vs baseline: 1.5760x; 1.0439x over previous
//
#include <hip/hip_runtime.h>

#define H   384
#define W   1280
#define PH  192
#define PW  640
#define PP  (PH*PW)      // 122880 pixels per pooled plane

typedef float f32x4 __attribute__((ext_vector_type(4)));
typedef int   i32x4 __attribute__((ext_vector_type(4)));

// ---------------------------------------------------------------------------
// Kernel A: 2x2 average pool + RGB->YCbCr for both images, both batches.
// Plane index p = img*2 + n  (img: 0=left, 1=right).
// Explicit round-to-nearest intrinsics in numpy evaluation order so the
// census '>=' comparisons match the reference bit-for-bit.
// ---------------------------------------------------------------------------
__global__ __launch_bounds__(256) void pool_ycbcr_kernel(
    const float* __restrict__ left, const float* __restrict__ right,
    float* __restrict__ yp, float* __restrict__ cbp, float* __restrict__ crp)
{
    int tid = blockIdx.x * blockDim.x + threadIdx.x;
    if (tid >= 4 * PP) return;
    int p   = tid / PP;
    int rem = tid - p * PP;
    int y   = rem / PW;
    int x   = rem - y * PW;

    const float* src = (p < 2 ? left : right) + (size_t)(p & 1) * 3 * H * W;

    float pc[3];
#pragma unroll
    for (int c = 0; c < 3; ++c) {
        const float* ch = src + (size_t)c * H * W + (size_t)(2 * y) * W + 2 * x;
        float2 a = *(const float2*)ch;
        float2 b = *(const float2*)(ch + W);
        float s = __fadd_rn(__fadd_rn(__fadd_rn(a.x, a.y), b.x), b.y);
        pc[c] = __fmul_rn(s, 0.25f);
    }
    float yv = __fadd_rn(__fadd_rn(__fmul_rn(0.299f, pc[0]),
                                   __fmul_rn(0.587f, pc[1])),
                         __fmul_rn(0.114f, pc[2]));
    float cb = __fadd_rn(__fmul_rn(__fsub_rn(pc[2], yv), 0.564f), 0.5f);
    float cr = __fadd_rn(__fmul_rn(__fsub_rn(pc[0], yv), 0.713f), 0.5f);

    yp[tid]  = yv;
    cbp[tid] = cb;
    crp[tid] = cr;
}

// ---------------------------------------------------------------------------
// Kernel B: 5x5 census transform (24 bits, MSB = offset (0,0)), zero border.
// ---------------------------------------------------------------------------
__global__ __launch_bounds__(256) void census_kernel(
    const float* __restrict__ yp, int* __restrict__ cen)
{
    int tid = blockIdx.x * blockDim.x + threadIdx.x;
    if (tid >= 4 * PP) return;
    int p   = tid / PP;
    int rem = tid - p * PP;
    int y   = rem / PW;
    int x   = rem - y * PW;

    int code = 0;
    if (y >= 2 && y < PH - 2 && x >= 2 && x < PW - 2) {
        const float* base = yp + (size_t)p * PP;
        float c = base[y * PW + x];
        int bit = 23;
#pragma unroll
        for (int v = 0; v < 5; ++v) {
#pragma unroll
            for (int u = 0; u < 5; ++u) {
                if (u == 2 && v == 2) continue;  // center excluded
                float nb = base[(y - 2 + v) * PW + (x - 2 + u)];
                code |= (nb >= c ? 1 : 0) << bit;
                --bit;
            }
        }
    }
    cen[tid] = code;
}

// ---------------------------------------------------------------------------
// Kernel C: cost volume + normalization, fused.
//   g=0: (popcount(cenL[x+d]^cenR[x]) - m1)/s1
//   g=1: (|cbL[x+d]-cbR[x]| - m2)/s2
//   g=2: (|crL[x+d]-crR[x]| - m3)/s3
// masked (x >= 640-d): 0 before normalization.
// Nontemporal float4 stores: the 377MB output stream must not evict the
// small L/R planes from L2 (they are re-read 128x per d-channel).
// XCD-aware chunked swizzle (6144 blocks % 8 XCDs == 0 -> bijective):
// each XCD serves 96 consecutive t-values -> <=2 (g,n) plane pairs
// (<=2MB) resident in its 4MB L2, instead of all 6 pairs (5.9MB) thrashing.
// ---------------------------------------------------------------------------
__global__ __launch_bounds__(256) void costvol_kernel(
    const float* __restrict__ cbp, const float* __restrict__ crp,
    const int* __restrict__ cen, float* __restrict__ out)
{
    const float m1 = 11.08282948f, i1 = 1.0f / 0.1949711f;
    const float m2 = 0.02175535f,  i2 = 1.0f / 35.91432953f;
    const float m3 = 0.02679042f,  i3 = 1.0f / 26.79782867f;

    // chunked XCD swizzle: XCD = blockIdx.x % 8 gets works [x*768, (x+1)*768)
    int b  = (blockIdx.x & 7) * 768 + (blockIdx.x >> 3);

    int yt = b & 7;           // y tile (24 rows each)
    int t  = b >> 3;
    int n  = t / 384;
    int ch = t - n * 384;
    int g  = ch >> 7;         // 0=ham, 1=u, 2=v  (block-uniform)
    int d  = ch & 127;
    int nvalid = PW - d;
    int y0 = yt * 24;
    int s  = d & 3;           // block-uniform shift
    int dal = d - s;          // aligned base offset
    const int tid = threadIdx.x;

    f32x4* ob = (f32x4*)(out + (((size_t)(n * 384 + ch)) * PH + y0) * PW);

    if (g == 0) {
        const float c0 = (0.0f - m1) * i1;
        const int* L = cen + (size_t)n * PP;        // left plane  (p = n)
        const int* R = cen + (size_t)(2 + n) * PP;  // right plane (p = 2+n)
#pragma unroll 5
        for (int k = 0; k < 15; ++k) {
            int i  = tid + 256 * k;
            int yy = i / 160;
            int x0 = (i - yy * 160) * 4;
            int row = (y0 + yy) * PW;
            i32x4 rv = *(const i32x4*)(R + row + x0);
            const int* Lp = L + row + x0 + dal;
            i32x4 A  = *(const i32x4*)(Lp);
            i32x4 Bv = *(const i32x4*)(Lp + 4);
            int e0, e1, e2, e3;
            if      (s == 0) { e0 = A.x;  e1 = A.y;  e2 = A.z;  e3 = A.w;  }
            else if (s == 1) { e0 = A.y;  e1 = A.z;  e2 = A.w;  e3 = Bv.x; }
            else if (s == 2) { e0 = A.z;  e1 = A.w;  e2 = Bv.x; e3 = Bv.y; }
            else             { e0 = A.w;  e1 = Bv.x; e2 = Bv.y; e3 = Bv.z; }
            f32x4 ov;
            ov.x = (x0 + 0 < nvalid) ? ((float)__popc(e0 ^ rv.x) - m1) * i1 : c0;
            ov.y = (x0 + 1 < nvalid) ? ((float)__popc(e1 ^ rv.y) - m1) * i1 : c0;
            ov.z = (x0 + 2 < nvalid) ? ((float)__popc(e2 ^ rv.z) - m1) * i1 : c0;
            ov.w = (x0 + 3 < nvalid) ? ((float)__popc(e3 ^ rv.w) - m1) * i1 : c0;
            __builtin_nontemporal_store(ov, ob + i);
        }
    } else {
        const float m  = (g == 1) ? m2 : m3;
        const float iv = (g == 1) ? i2 : i3;
        const float c0 = (0.0f - m) * iv;
        const float* P = (g == 1) ? cbp : crp;
        const float* L = P + (size_t)n * PP;
        const float* R = P + (size_t)(2 + n) * PP;
#pragma unroll 5
        for (int k = 0; k < 15; ++k) {
            int i  = tid + 256 * k;
            int yy = i / 160;
            int x0 = (i - yy * 160) * 4;
            int row = (y0 + yy) * PW;
            f32x4 rv = *(const f32x4*)(R + row + x0);
            const float* Lp = L + row + x0 + dal;
            f32x4 A  = *(const f32x4*)(Lp);
            f32x4 Bv = *(const f32x4*)(Lp + 4);
            float e0, e1, e2, e3;
            if      (s == 0) { e0 = A.x;  e1 = A.y;  e2 = A.z;  e3 = A.w;  }
            else if (s == 1) { e0 = A.y;  e1 = A.z;  e2 = A.w;  e3 = Bv.x; }
            else if (s == 2) { e0 = A.z;  e1 = A.w;  e2 = Bv.x; e3 = Bv.y; }
            else             { e0 = A.w;  e1 = Bv.x; e2 = Bv.y; e3 = Bv.z; }
            f32x4 ov;
            ov.x = (x0 + 0 < nvalid) ? (fabsf(e0 - rv.x) - m) * iv : c0;
            ov.y = (x0 + 1 < nvalid) ? (fabsf(e1 - rv.y) - m) * iv : c0;
            ov.z = (x0 + 2 < nvalid) ? (fabsf(e2 - rv.z) - m) * iv : c0;
            ov.w = (x0 + 3 < nvalid) ? (fabsf(e3 - rv.w) - m) * iv : c0;
            __builtin_nontemporal_store(ov, ob + i);
        }
    }
}

// ---------------------------------------------------------------------------
extern "C" void kernel_launch(void* const* d_in, const int* in_sizes, int n_in,
                              void* d_out, int out_size, void* d_ws, size_t ws_size,
                              hipStream_t stream)
{
    const float* left  = (const float*)d_in[0];
    const float* right = (const float*)d_in[1];

    float* ws  = (float*)d_ws;
    float* yp  = ws;                     // 4 planes of PP floats
    float* cbp = ws + 4 * PP;
    float* crp = ws + 8 * PP;
    int*   cen = (int*)(ws + 12 * PP);   // 4 planes of PP int32 (aligned-vector
                                         // overread needs ~512B slack after)

    int threads = 256;
    int blocksAB = (4 * PP + threads - 1) / threads;   // 1920

    pool_ycbcr_kernel<<<blocksAB, threads, 0, stream>>>(left, right, yp, cbp, crp);
    census_kernel<<<blocksAB, threads, 0, stream>>>(yp, cen);

    int blocksC = 2 * 384 * 8;   // 6144
    costvol_kernel<<<blocksC, threads, 0, stream>>>(cbp, crp, cen, (float*)d_out);
}